// Round 10
// baseline (133.198 us; speedup 1.0000x reference)
//
#include <hip/hip_runtime.h>
#include <hip/hip_bf16.h>
#include <math.h>

#define B_    16
#define T1_   64
#define T2_   64
#define D_    1024
#define PROJ_ 512
#define BM    64
#define NKH   16                 // k-steps (of 32) per K-half
#define HALFK 512                // k per half

typedef __attribute__((ext_vector_type(8))) short bf16x8;
typedef __attribute__((ext_vector_type(4))) float f32x4;
typedef __attribute__((ext_vector_type(4))) unsigned int u32x4;

// RNE fp32->bf16, no NaN path (inputs are finite)
__device__ __forceinline__ unsigned short f2bf(float f) {
  unsigned int u = __builtin_bit_cast(unsigned int, f);
  u += 0x7FFFu + ((u >> 16) & 1u);
  return (unsigned short)(u >> 16);
}

// tanh(a) = 1 - 2/(exp(2a)+1); v_exp_f32 + v_rcp_f32, ~5 instr, |err|~1e-6
__device__ __forceinline__ float fast_tanh(float a) {
  float t = __builtin_amdgcn_exp2f(a * 2.885390081777927f);  // exp(2a)
  return 1.0f - 2.0f * __builtin_amdgcn_rcpf(t + 1.0f);
}

// ---------------------------------------------------------------------------
// Prep: Wt fragment-ordered bf16. 16B chunk index ((t32*32 + n16)*64 + lane)
// holds W[k][n], n = n16*16 + (lane&15), k = t32*32 + (lane>>4)*8 + j.
// ---------------------------------------------------------------------------
__global__ __launch_bounds__(256) void make_bfrag(
    const float* __restrict__ W, unsigned short* __restrict__ wt) {
  __shared__ float tile[32][33];
  const int t  = blockIdx.x;        // k-step 0..31
  const int np = blockIdx.y;        // n-pair 0..15
  const int tx = threadIdx.x & 31;
  const int ty = threadIdx.x >> 5;  // 0..7
#pragma unroll
  for (int i = 0; i < 4; ++i)
    tile[ty + i * 8][tx] =
        W[(size_t)(t * 32 + ty + i * 8) * PROJ_ + np * 32 + tx];
  __syncthreads();
  if (threadIdx.x < 128) {
    const int sub  = threadIdx.x >> 6;   // 0..1
    const int lane = threadIdx.x & 63;
    const int llo = lane & 15, lhi = lane >> 4;
    unsigned short o[8];
#pragma unroll
    for (int j = 0; j < 8; ++j)
      o[j] = f2bf(tile[lhi * 8 + j][sub * 16 + llo]);
    const int n16 = np * 2 + sub;
    *(u32x4*)(wt + ((size_t)(t * 32 + n16) * 64 + lane) * 8) = *(const u32x4*)o;
  }
}

// ---------------------------------------------------------------------------
// scores_kernel: one (b,t1) group of 64 rows per 512-thread block (8 waves).
// attn[bt][s] = softmax_s( v . tanh(x[bt,s,:] @ W) )  -> d_ws
// K in 2 halves; per half: stage A (64x512 bf16, XOR-swizzled) into 64 KB
// LDS once, then a barrier-free K-loop (LDS read-only; waves autonomous).
// Spill-free: STAGE unroll 2 (~16 live staging regs), B refreshed after use.
// ---------------------------------------------------------------------------
__global__ __launch_bounds__(512, 4) void scores_kernel(
    const float* __restrict__ x, const unsigned short* __restrict__ wt,
    const float* __restrict__ v, float* __restrict__ attnws) {
  __shared__ __align__(16) char smem[65536];      // A half-tile; sp overlays
  float (*sp)[9] = (float(*)[9])smem;             // 2304 B (after K loops)

  const int tid  = threadIdx.x;
  const int lane = tid & 63;
  const int wid  = tid >> 6;            // 0..7 = 64-col n-slice
  const int llo  = lane & 15, lhi = lane >> 4;
  const int swz  = (llo & 7) << 4;      // A-read swizzle (row&7 == llo&7)
  const int bt   = blockIdx.x;
  const int m0   = bt * BM;

  f32x4 acc[4][4];
#pragma unroll
  for (int mf = 0; mf < 4; ++mf)
#pragma unroll
    for (int nf = 0; nf < 4; ++nf) acc[mf][nf] = (f32x4){0.f, 0.f, 0.f, 0.f};

  const u32x4* wt4 = (const u32x4*)wt;  // chunk idx (t32*32 + n16)*64 + lane
  const int bbase = (wid * 4) * 64 + lane;

  // B(t32=0) prefetch (latency covered by staging)
  u32x4 rb[4];
#pragma unroll
  for (int nf = 0; nf < 4; ++nf) rb[nf] = wt4[bbase + nf * 64];

  // stage half H of A -> LDS bf16 swizzled; unroll 2 keeps regs lean
#define STAGE(H)                                                              \
  {                                                                           \
    _Pragma("unroll 2")                                                       \
    for (int r = 0; r < 8; ++r) {                                             \
      const int p = r * 512 + tid;                                            \
      const int row = p >> 6, pc = p & 63;                                    \
      const float* s = x + (size_t)(m0 + row) * D_ + (H) * HALFK + pc * 8;    \
      float4 a = *(const float4*)s;                                           \
      float4 b = *(const float4*)(s + 4);                                     \
      unsigned short o[8] = {f2bf(a.x), f2bf(a.y), f2bf(a.z), f2bf(a.w),      \
                             f2bf(b.x), f2bf(b.y), f2bf(b.z), f2bf(b.w)};     \
      const int db = (row * 1024 + pc * 16) ^ ((row & 7) << 4);               \
      *(u32x4*)(smem + db) = *(const u32x4*)o;                                \
    }                                                                         \
  }

  // barrier-free K-loop over half H (16 steps), R4-style B refresh-after-use
#define KLOOP(H)                                                              \
  {                                                                           \
    _Pragma("unroll 2")                                                       \
    for (int ks = 0; ks < NKH; ++ks) {                                        \
      const int t32 = (H) * NKH + ks;                                         \
      const int kb = ks * 64 + lhi * 16;                                      \
      bf16x8 af0 = *(const bf16x8*)(smem + ((( 0 + llo) * 1024 + kb) ^ swz)); \
      bf16x8 af1 = *(const bf16x8*)(smem + (((16 + llo) * 1024 + kb) ^ swz)); \
      bf16x8 af2 = *(const bf16x8*)(smem + (((32 + llo) * 1024 + kb) ^ swz)); \
      bf16x8 af3 = *(const bf16x8*)(smem + (((48 + llo) * 1024 + kb) ^ swz)); \
      __builtin_amdgcn_s_setprio(1);                                          \
      _Pragma("unroll")                                                       \
      for (int nf = 0; nf < 4; ++nf) {                                        \
        bf16x8 bfr = *(const bf16x8*)&rb[nf];                                 \
        acc[0][nf] = __builtin_amdgcn_mfma_f32_16x16x32_bf16(af0, bfr, acc[0][nf], 0, 0, 0); \
        acc[1][nf] = __builtin_amdgcn_mfma_f32_16x16x32_bf16(af1, bfr, acc[1][nf], 0, 0, 0); \
        acc[2][nf] = __builtin_amdgcn_mfma_f32_16x16x32_bf16(af2, bfr, acc[2][nf], 0, 0, 0); \
        acc[3][nf] = __builtin_amdgcn_mfma_f32_16x16x32_bf16(af3, bfr, acc[3][nf], 0, 0, 0); \
        if (t32 + 1 < 32)                                                     \
          rb[nf] = wt4[(size_t)(t32 + 1) * 2048 + bbase + nf * 64];           \
      }                                                                       \
      __builtin_amdgcn_s_setprio(0);                                          \
    }                                                                         \
  }

  STAGE(0)
  __syncthreads();
  KLOOP(0)
  __syncthreads();        // reads of half 0 done
  STAGE(1)
  __syncthreads();
  KLOOP(1)
  __syncthreads();        // A LDS free; sp overlays
#undef STAGE
#undef KLOOP

  // tanh + dot(v-slice) + 16-lane reduce -> sp[row][wid]
  {
    const float vv0 = v[wid * 64 +  0 + llo];
    const float vv1 = v[wid * 64 + 16 + llo];
    const float vv2 = v[wid * 64 + 32 + llo];
    const float vv3 = v[wid * 64 + 48 + llo];
#pragma unroll
    for (int mf = 0; mf < 4; ++mf) {
      float pr[4] = {0.f, 0.f, 0.f, 0.f};
#pragma unroll
      for (int r = 0; r < 4; ++r) {
        pr[r] += fast_tanh(acc[mf][0][r]) * vv0;
        pr[r] += fast_tanh(acc[mf][1][r]) * vv1;
        pr[r] += fast_tanh(acc[mf][2][r]) * vv2;
        pr[r] += fast_tanh(acc[mf][3][r]) * vv3;
      }
#pragma unroll
      for (int r = 0; r < 4; ++r) {
        float p = pr[r];
        p += __shfl_xor(p, 1, 64);
        p += __shfl_xor(p, 2, 64);
        p += __shfl_xor(p, 4, 64);
        p += __shfl_xor(p, 8, 64);
        if (llo == 0) sp[mf * 16 + lhi * 4 + r][wid] = p;
      }
    }
  }
  __syncthreads();

  // softmax over the 64 rows (wave 0) -> attn weights to global ws
  if (tid < BM) {
    float s = 0.f;
#pragma unroll
    for (int w = 0; w < 8; ++w) s += sp[tid][w];
    float mx = s;
#pragma unroll
    for (int mask = 1; mask < 64; mask <<= 1)
      mx = fmaxf(mx, __shfl_xor(mx, mask, 64));
    const float e = __builtin_amdgcn_exp2f((s - mx) * 1.442695040888963f);
    float sum = e;
#pragma unroll
    for (int mask = 1; mask < 64; mask <<= 1)
      sum += __shfl_xor(sum, mask, 64);
    attnws[bt * BM + tid] = e * __builtin_amdgcn_rcpf(sum);
  }
}

// ---------------------------------------------------------------------------
// out_kernel: out[bt,:] = sum_s attn[bt,s] * x[bt,s,:]. One block per bt,
// 256 threads x one float4 column each, MLP=4. Pure streaming (256 KB/block).
// ---------------------------------------------------------------------------
__global__ __launch_bounds__(256) void out_kernel(
    const float* __restrict__ x, const float* __restrict__ attnws,
    float* __restrict__ out) {
  const int bt  = blockIdx.x;
  const int tid = threadIdx.x;
  __shared__ float attn[T2_];
  if (tid < T2_) attn[tid] = attnws[bt * T2_ + tid];
  __syncthreads();

  const float* xg = x + (size_t)bt * (T2_ * D_) + tid * 4;
  f32x4 o0 = {0.f,0.f,0.f,0.f}, o1 = o0, o2 = o0, o3 = o0;
#pragma unroll 4
  for (int s = 0; s < T2_; s += 4) {
    const float w0 = attn[s + 0];
    const float w1 = attn[s + 1];
    const float w2 = attn[s + 2];
    const float w3 = attn[s + 3];
    const float4 a0 = *(const float4*)(xg + (size_t)(s + 0) * D_);
    const float4 a1 = *(const float4*)(xg + (size_t)(s + 1) * D_);
    const float4 a2 = *(const float4*)(xg + (size_t)(s + 2) * D_);
    const float4 a3 = *(const float4*)(xg + (size_t)(s + 3) * D_);
    o0[0] += w0 * a0.x; o0[1] += w0 * a0.y; o0[2] += w0 * a0.z; o0[3] += w0 * a0.w;
    o1[0] += w1 * a1.x; o1[1] += w1 * a1.y; o1[2] += w1 * a1.z; o1[3] += w1 * a1.w;
    o2[0] += w2 * a2.x; o2[1] += w2 * a2.y; o2[2] += w2 * a2.z; o2[3] += w2 * a2.w;
    o3[0] += w3 * a3.x; o3[1] += w3 * a3.y; o3[2] += w3 * a3.z; o3[3] += w3 * a3.w;
  }
  float4 res = {(o0[0] + o1[0]) + (o2[0] + o3[0]),
                (o0[1] + o1[1]) + (o2[1] + o3[1]),
                (o0[2] + o1[2]) + (o2[2] + o3[2]),
                (o0[3] + o1[3]) + (o2[3] + o3[3])};
  *(float4*)(out + (size_t)bt * D_ + tid * 4) = res;
}

extern "C" void kernel_launch(void* const* d_in, const int* in_sizes, int n_in,
                              void* d_out, int out_size, void* d_ws, size_t ws_size,
                              hipStream_t stream) {
  const float* x = (const float*)d_in[0];   // (16,64,64,1024) fp32
  const float* W = (const float*)d_in[1];   // (1024,512) fp32
  const float* v = (const float*)d_in[2];   // (512,) fp32
  float* out = (float*)d_out;               // (16,64,1024) fp32
  unsigned short* Wt = (unsigned short*)d_ws;            // 1 MB fragment-ordered bf16
  float* attnws = (float*)((char*)d_ws + (1 << 20));     // 256 KB attn weights

  make_bfrag<<<dim3(32, PROJ_ / 32), 256, 0, stream>>>(W, Wt);
  scores_kernel<<<B_ * T1_, 512, 0, stream>>>(x, Wt, v, attnws);
  out_kernel<<<B_ * T1_, 256, 0, stream>>>(x, attnws, out);
}